// Round 4
// baseline (257.599 us; speedup 1.0000x reference)
//
#include <hip/hip_runtime.h>
#include <stdint.h>

// ---- Paillier constants (P=59, Q=61) ----
static constexpr uint32_t PP  = 59, QQ = 61;
static constexpr uint32_t Nn  = PP * QQ;        // 3599
static constexpr uint32_t P2  = PP * PP;        // 3481
static constexpr uint32_t Q2  = QQ * QQ;        // 3721
static constexpr uint32_t LAM = 1740;           // lcm(58,60)

constexpr uint32_t cinv(uint32_t a, uint32_t m) {   // brute-force modular inverse
    for (uint32_t x = 1; x < m; ++x) if ((uint64_t)a * x % m == 1u) return x;
    return 0u;
}
static constexpr uint32_t MU  = cinv(LAM % Nn, Nn);   // 1119 = lambda^-1 mod n
static constexpr uint32_t IQP = cinv(P2 % Q2, Q2);    // (p^2)^-1 mod q^2
static constexpr uint32_t GAM = cinv(PP % QQ, QQ);    // p^-1 mod q = 30
static constexpr uint32_t CPP = (cinv(QQ % PP, PP) * (MU % PP)) % PP;  // q^-1*mu mod p
static constexpr uint32_t CQQ = (cinv(PP % QQ, QQ) * (MU % QQ)) % QQ;  // p^-1*mu mod q

static constexpr int TPN = 3484;                // Tp u32 count (3481 padded to /4)
static constexpr int TQN = 3724;                // Tq u32 count (3721 padded to /4)
static constexpr int TT  = TPN + TQN;           // 7208 u32 = 28832 B
static constexpr size_t WS_NEED = (size_t)TT * 4;

typedef uint32_t u32x4 __attribute__((ext_vector_type(4)));
typedef float    f32x4 __attribute__((ext_vector_type(4)));

// ---- full-rate 24-bit multiplies (operands provably < 2^24) ----
__device__ __forceinline__ uint32_t mul24lo(uint32_t a, uint32_t b) {
    uint32_t r;
    asm("v_mul_u32_u24 %0, %1, %2" : "=v"(r) : "v"(a), "v"(b));
    return r;
}
__device__ __forceinline__ uint32_t mul24hi(uint32_t a, uint32_t b) {
    uint32_t r;                                   // (u24(a)*u24(b)) >> 32
    asm("v_mul_hi_u32_u24 %0, %1, %2" : "=v"(r) : "v"(a), "v"(b));
    return r;
}
__device__ __forceinline__ uint32_t mad24_59(uint32_t a, uint32_t c) {
    uint32_t r;                                   // a*59 + c, all < 2^24
    asm("v_mad_u32_u24 %0, %1, 59, %2" : "=v"(r) : "v"(a), "v"(c));
    return r;
}

// x < 2^24, D ~ 3500: x mod D via 2^32 magic (no shift needed). Exact.
template<uint32_t D>
__device__ __forceinline__ uint32_t mod24(uint32_t x) {
    constexpr uint32_t M = (uint32_t)((1ull << 32) / D);
    uint32_t q = mul24hi(x, M);
    uint32_t r = x - mul24lo(q, D);           // ∈ [0, 2D)
    return min(r, r - D);                     // unsigned wrap trick
}

// ---- table construction (exact; runs once over 3724 threads) ----
template<uint32_t MOD>
__device__ uint32_t pow1740(uint32_t base) {
    uint32_t b = base % MOD, r = 1u, e = LAM;
    while (e) {                               // products < MOD^2 < 2^24
        if (e & 1u) r = (r * b) % MOD;
        b = (b * b) % MOD;
        e >>= 1u;
    }
    return r;
}
__device__ uint32_t m_from_r(uint32_t r) {
    if (r == 0u) return Nn - MU;              // x = -1 -> (-mu) mod n = 2480
    uint32_t x = (r - 1u) / Nn;               // exact floor, x < n
    return (x * MU) % Nn;                     // < 3599*1119 < 2^22
}
// Tp[ip]: bits0-5 g_p, bits8-13 m_p, bits16-27 dq_val (m when q|c), bit31 p|ip
__device__ uint32_t tp_entry(uint32_t i) {
    uint32_t a = pow1740<P2>(i);              // c^lam mod p^2 (0 iff p|i)
    uint32_t flag = (i % PP == 0u) ? 0x80000000u : 0u;
    uint32_t gp = 0u, mp = 0u;
    if (!flag) {                              // a ≡ 1 mod p; s = (a-1)/p
        uint32_t s = (a - 1u) / PP;
        mp = (s * CPP) % PP;                  // m mod p
        gp = (mp * GAM) % QQ;
    }
    uint32_t t = (uint32_t)(((uint64_t)((Q2 - a % Q2) % Q2) * IQP) % Q2);
    uint32_t r = a + P2 * t;                  // < n^2, exact
    uint32_t dq = m_from_r(r);                // flag case: a=0 -> r=0 -> 2480
    return gp | (mp << 8) | (dq << 16) | flag;
}
// Tq[iq]: bits0-5 g_q, bits16-27 dp_val (m when p|c), bit31 q|iq
__device__ uint32_t tq_entry(uint32_t i) {
    uint32_t b = pow1740<Q2>(i);              // c^lam mod q^2 (0 iff q|i)
    uint32_t flag = (i % QQ == 0u) ? 0x80000000u : 0u;
    uint32_t gq = 0u;
    if (!flag) {
        uint32_t s = (b - 1u) / QQ;
        uint32_t mq = (s * CQQ) % QQ;         // m mod q
        gq = (mq * GAM) % QQ;
    }
    uint32_t t = (uint32_t)(((uint64_t)b * IQP) % Q2);
    uint32_t r = P2 * t;                      // < n^2, exact
    uint32_t dp = m_from_r(r);                // flag case: b=0 -> r=0 -> 2480
    return gq | (dp << 16) | flag;
}

__global__ void build_tables(uint32_t* __restrict__ T) {
    int i = blockIdx.x * blockDim.x + threadIdx.x;
    if (i < TPN) T[i]       = (i < (int)P2) ? tp_entry((uint32_t)i) : 0u;
    if (i < TQN) T[TPN + i] = (i < (int)Q2) ? tq_entry((uint32_t)i) : 0u;
}

// ---- per-element decrypt: ~22 VALU ops + 2 LDS gathers, exact for ALL c ----
__device__ __forceinline__ float dec1(uint32_t c, const uint32_t* sTp,
                                      const uint32_t* sTq, float scale) {
    uint32_t up = sTp[mod24<P2>(c)];
    uint32_t uq = sTq[mod24<Q2>(c)];
    uint32_t gp  = up & 63u;
    uint32_t mp  = (up >> 8) & 63u;
    uint32_t dqv = (up >> 16) & 0xFFFu;
    uint32_t gq  = uq & 63u;
    uint32_t dpv = (uq >> 16) & 0xFFFu;
    uint32_t d = gq + QQ - gp;                // (m_q - m_p)*p^-1 mod q, premult
    d = min(d, d - QQ);
    uint32_t m = mad24_59(d, mp);             // CRT: m_p + 59*d ∈ [0, 3599)
    m = ((int32_t)uq < 0) ? dqv : m;          // q|c: table value from ip
    m = ((int32_t)up < 0) ? dpv : m;          // p|c: table value from iq (2480 if both)
    return fmaxf((float)m * scale, 0.0f);     // relu(m * (inv_scale/1000))
}

__device__ __forceinline__ f32x4 dec4v(u32x4 a, const uint32_t* sTp,
                                       const uint32_t* sTq, float scale) {
    f32x4 o;
    o.x = dec1(a.x, sTp, sTq, scale);
    o.y = dec1(a.y, sTp, sTq, scale);
    o.z = dec1(a.z, sTp, sTq, scale);
    o.w = dec1(a.w, sTp, sTq, scale);
    return o;
}

#define BLK 512

// ---- hand-scheduled VMEM (all volatile asm => issue order == source order) --
#define LD4(A, VOFF, BASE) \
    asm volatile("global_load_dwordx4 %0, %1, %2" \
                 : "=&v"(A) : "v"(VOFF), "s"(BASE))
#define ST4NT(VOFF, O, BASE) \
    asm volatile("global_store_dwordx4 %0, %1, %2 nt" \
                 :: "v"(VOFF), "v"(O), "s"(BASE))

// ALL-LOADS-FIRST schedule.  vmcnt is one in-order FIFO for loads AND stores:
// a wait needing load L must first retire every store OLDER than L.  Rounds
// 0-2 all gated compute on a recent store's ack (0/1/4 slots old) and all ran
// ~86us => store acks under write congestion are multi-us.  Round 3 tried to
// dodge this but (a) still had stores older than later-waited loads and
// (b) CORRUPTED DATA: store-source VGPRs are read asynchronously after issue,
// and dropping the liveness tie let the allocator reuse them (absmax 3.59).
//
// Here: issue all 16 loads up front, then 16 slots of {wait, dec, store}.
// Before slot k: outstanding = (16-k) loads + k stores = 16, and EVERY store
// is younger than EVERY remaining load -> vmcnt(15) retires exactly L_k and
// can never require a store ack.  Store-source quads o0..o15 stay live to the
// end of the kernel (keepalive asm) so no WAR reuse; stores drain at endpgm.
// Peak regs ~ 64(a, dying) + 64(o, growing) overlap ≈ 85 -> bounds (512,4).
#define SLOT(A, O) do {                                     \
    asm volatile("s_waitcnt vmcnt(15)" : "+v"(A));          \
    O = dec4v(A, sTp, sTq, scale);                          \
    ST4NT(voff_st, O, out); voff_st += s16;                 \
} while (0)

// Exactly-16-iterations kernel: 1024 blocks x 512 thr, n4 == 16*stride.
__global__ __launch_bounds__(BLK, 4) void paillier_main16(
        const uint32_t* __restrict__ in4, float* __restrict__ out,
        const uint32_t* __restrict__ T, const float* __restrict__ inv_scale,
        int n4) {
    __shared__ uint32_t sT[TT];
    for (int k = threadIdx.x; k < TT / 4; k += BLK)
        ((uint4*)sT)[k] = ((const uint4*)T)[k];

    float scale = inv_scale[0] / 1000.0f;     // matches reference fp32 op order
    asm volatile("" :: "v"(scale));           // drain this scalar load now, not
                                              // inside the counted main FIFO
    __syncthreads();                          // also drains table-copy VMEM
    const uint32_t* sTp = sT;
    const uint32_t* sTq = sT + TPN;

    const uint32_t s16 = (uint32_t)(gridDim.x * BLK) * 16u;   // byte stride
    uint32_t voff_ld = (uint32_t)(blockIdx.x * BLK + threadIdx.x) * 16u;
    uint32_t voff_st = voff_ld;

    u32x4 a0, a1, a2, a3, a4, a5, a6, a7, a8, a9, a10, a11, a12, a13, a14, a15;
    f32x4 o0, o1, o2, o3, o4, o5, o6, o7, o8, o9, o10, o11, o12, o13, o14, o15;

    LD4(a0,  voff_ld, in4); voff_ld += s16;   // L0..L15: 16 loads in flight
    LD4(a1,  voff_ld, in4); voff_ld += s16;
    LD4(a2,  voff_ld, in4); voff_ld += s16;
    LD4(a3,  voff_ld, in4); voff_ld += s16;
    LD4(a4,  voff_ld, in4); voff_ld += s16;
    LD4(a5,  voff_ld, in4); voff_ld += s16;
    LD4(a6,  voff_ld, in4); voff_ld += s16;
    LD4(a7,  voff_ld, in4); voff_ld += s16;
    LD4(a8,  voff_ld, in4); voff_ld += s16;
    LD4(a9,  voff_ld, in4); voff_ld += s16;
    LD4(a10, voff_ld, in4); voff_ld += s16;
    LD4(a11, voff_ld, in4); voff_ld += s16;
    LD4(a12, voff_ld, in4); voff_ld += s16;
    LD4(a13, voff_ld, in4); voff_ld += s16;
    LD4(a14, voff_ld, in4); voff_ld += s16;
    LD4(a15, voff_ld, in4); voff_ld += s16;

    SLOT(a0,  o0);   SLOT(a1,  o1);   SLOT(a2,  o2);   SLOT(a3,  o3);
    SLOT(a4,  o4);   SLOT(a5,  o5);   SLOT(a6,  o6);   SLOT(a7,  o7);
    SLOT(a8,  o8);   SLOT(a9,  o9);   SLOT(a10, o10);  SLOT(a11, o11);
    SLOT(a12, o12);  SLOT(a13, o13);  SLOT(a14, o14);  SLOT(a15, o15);

    // Keep every store-source quad live until endpgm: outstanding stores read
    // their VGPRs asynchronously; reuse before drain corrupts output (round 3).
    asm volatile("" ::
        "v"(o0), "v"(o1), "v"(o2),  "v"(o3),  "v"(o4),  "v"(o5),  "v"(o6),  "v"(o7),
        "v"(o8), "v"(o9), "v"(o10), "v"(o11), "v"(o12), "v"(o13), "v"(o14), "v"(o15));
    // trailing stores drain at s_endpgm
}

// Generic grid-stride path (any n4; also the tail-capable fallback).
__device__ __forceinline__ void dec_loop_gen(const uint4* __restrict__ in4,
                                             float4* __restrict__ out,
                                             const uint32_t* sTp,
                                             const uint32_t* sTq,
                                             float scale, int n4) {
    int stride = gridDim.x * BLK;
    for (int i = blockIdx.x * BLK + threadIdx.x; i < n4; i += stride) {
        uint4 a = in4[i];
        float4 o;
        o.x = dec1(a.x, sTp, sTq, scale);
        o.y = dec1(a.y, sTp, sTq, scale);
        o.z = dec1(a.z, sTp, sTq, scale);
        o.w = dec1(a.w, sTp, sTq, scale);
        out[i] = o;
    }
}

__global__ __launch_bounds__(BLK) void paillier_main_gen(
        const uint4* __restrict__ in4, float4* __restrict__ out,
        const uint32_t* __restrict__ T, const float* __restrict__ inv_scale,
        int n4) {
    __shared__ uint32_t sT[TT];
    for (int k = threadIdx.x; k < TT / 4; k += BLK)
        ((uint4*)sT)[k] = ((const uint4*)T)[k];
    __syncthreads();
    float scale = inv_scale[0] / 1000.0f;
    dec_loop_gen(in4, out, sT, sT + TPN, scale, n4);
}

// Fallback (ws too small): build packed tables in-block, same generic path.
__global__ __launch_bounds__(BLK) void paillier_main_fb(
        const uint4* __restrict__ in4, float4* __restrict__ out,
        const float* __restrict__ inv_scale, int n4) {
    __shared__ uint32_t sT[TT];
    for (int i = threadIdx.x; i < (int)P2; i += BLK) sT[i]       = tp_entry((uint32_t)i);
    for (int i = threadIdx.x; i < (int)Q2; i += BLK) sT[TPN + i] = tq_entry((uint32_t)i);
    __syncthreads();
    float scale = inv_scale[0] / 1000.0f;
    dec_loop_gen(in4, out, sT, sT + TPN, scale, n4);
}

extern "C" void kernel_launch(void* const* d_in, const int* in_sizes, int n_in,
                              void* d_out, int out_size, void* d_ws, size_t ws_size,
                              hipStream_t stream) {
    const uint4* c        = (const uint4*)d_in[0];     // int32 data, read as uint4
    const float* invscale = (const float*)d_in[1];
    float4* out           = (float4*)d_out;

    int n  = in_sizes[0];                              // 33,554,432
    int n4 = n / 4;

    int nblk = 1024;
    int need = (n4 + BLK - 1) / BLK;
    if (nblk > need) nblk = need;

    bool exact16 = (nblk == 1024) && (n4 == 16 * nblk * BLK);

    if (ws_size >= WS_NEED && d_ws != nullptr) {
        uint32_t* T = (uint32_t*)d_ws;
        build_tables<<<(TQN + 255) / 256, 256, 0, stream>>>(T);
        if (exact16) {
            paillier_main16<<<nblk, BLK, 0, stream>>>(
                (const uint32_t*)c, (float*)out, T, invscale, n4);
        } else {
            paillier_main_gen<<<nblk, BLK, 0, stream>>>(c, out, T, invscale, n4);
        }
    } else {
        paillier_main_fb<<<nblk, BLK, 0, stream>>>(c, out, invscale, n4);
    }
}

// Round 7
// 226.828 us; speedup vs baseline: 1.1357x; 1.1357x over previous
//
#include <hip/hip_runtime.h>
#include <stdint.h>

// ---- Paillier constants (P=59, Q=61) ----
static constexpr uint32_t PP  = 59, QQ = 61;
static constexpr uint32_t Nn  = PP * QQ;        // 3599
static constexpr uint32_t P2  = PP * PP;        // 3481
static constexpr uint32_t Q2  = QQ * QQ;        // 3721
static constexpr uint32_t LAM = 1740;           // lcm(58,60)

constexpr uint32_t cinv(uint32_t a, uint32_t m) {   // brute-force modular inverse
    for (uint32_t x = 1; x < m; ++x) if ((uint64_t)a * x % m == 1u) return x;
    return 0u;
}
static constexpr uint32_t MU  = cinv(LAM % Nn, Nn);   // 1119 = lambda^-1 mod n
static constexpr uint32_t IQP = cinv(P2 % Q2, Q2);    // (p^2)^-1 mod q^2
static constexpr uint32_t GAM = cinv(PP % QQ, QQ);    // p^-1 mod q = 30
static constexpr uint32_t CPP = (cinv(QQ % PP, PP) * (MU % PP)) % PP;  // q^-1*mu mod p
static constexpr uint32_t CQQ = (cinv(PP % QQ, QQ) * (MU % QQ)) % QQ;  // p^-1*mu mod q

static constexpr int TPN = 3484;                // Tp u32 count (3481 padded to /4)
static constexpr int TQN = 3724;                // Tq u32 count (3721 padded to /4)
static constexpr int TT  = TPN + TQN;           // 7208 u32 = 28832 B
static constexpr size_t WS_NEED = (size_t)TT * 4;

typedef uint32_t u32x4 __attribute__((ext_vector_type(4)));   // builtin-compatible

// ---- full-rate 24-bit multiplies (operands provably < 2^24) ----
__device__ __forceinline__ uint32_t mul24lo(uint32_t a, uint32_t b) {
    uint32_t r;
    asm("v_mul_u32_u24 %0, %1, %2" : "=v"(r) : "v"(a), "v"(b));
    return r;
}
__device__ __forceinline__ uint32_t mul24hi(uint32_t a, uint32_t b) {
    uint32_t r;                                   // (u24(a)*u24(b)) >> 32
    asm("v_mul_hi_u32_u24 %0, %1, %2" : "=v"(r) : "v"(a), "v"(b));
    return r;
}
__device__ __forceinline__ uint32_t mad24_59(uint32_t a, uint32_t c) {
    uint32_t r;                                   // a*59 + c, all < 2^24
    asm("v_mad_u32_u24 %0, %1, 59, %2" : "=v"(r) : "v"(a), "v"(c));
    return r;
}

// x < 2^24, D ~ 3500: x mod D via 2^32 magic (no shift needed). Exact.
template<uint32_t D>
__device__ __forceinline__ uint32_t mod24(uint32_t x) {
    constexpr uint32_t M = (uint32_t)((1ull << 32) / D);
    uint32_t q = mul24hi(x, M);
    uint32_t r = x - mul24lo(q, D);           // ∈ [0, 2D)
    return min(r, r - D);                     // unsigned wrap trick
}

// ---- table construction (exact; runs once over 3724 threads) ----
template<uint32_t MOD>
__device__ uint32_t pow1740(uint32_t base) {
    uint32_t b = base % MOD, r = 1u, e = LAM;
    while (e) {                               // products < MOD^2 < 2^24
        if (e & 1u) r = (r * b) % MOD;
        b = (b * b) % MOD;
        e >>= 1u;
    }
    return r;
}
__device__ uint32_t m_from_r(uint32_t r) {
    if (r == 0u) return Nn - MU;              // x = -1 -> (-mu) mod n = 2480
    uint32_t x = (r - 1u) / Nn;               // exact floor, x < n
    return (x * MU) % Nn;                     // < 3599*1119 < 2^22
}
// Tp[ip]: bits0-5 g_p, bits8-13 m_p, bits16-27 dq_val (m when q|c), bit31 p|ip
__device__ uint32_t tp_entry(uint32_t i) {
    uint32_t a = pow1740<P2>(i);              // c^lam mod p^2 (0 iff p|i)
    uint32_t flag = (i % PP == 0u) ? 0x80000000u : 0u;
    uint32_t gp = 0u, mp = 0u;
    if (!flag) {                              // a ≡ 1 mod p; s = (a-1)/p
        uint32_t s = (a - 1u) / PP;
        mp = (s * CPP) % PP;                  // m mod p
        gp = (mp * GAM) % QQ;
    }
    uint32_t t = (uint32_t)(((uint64_t)((Q2 - a % Q2) % Q2) * IQP) % Q2);
    uint32_t r = a + P2 * t;                  // < n^2, exact
    uint32_t dq = m_from_r(r);                // flag case: a=0 -> r=0 -> 2480
    return gp | (mp << 8) | (dq << 16) | flag;
}
// Tq[iq]: bits0-5 g_q, bits16-27 dp_val (m when p|c), bit31 q|iq
__device__ uint32_t tq_entry(uint32_t i) {
    uint32_t b = pow1740<Q2>(i);              // c^lam mod q^2 (0 iff q|i)
    uint32_t flag = (i % QQ == 0u) ? 0x80000000u : 0u;
    uint32_t gq = 0u;
    if (!flag) {
        uint32_t s = (b - 1u) / QQ;
        uint32_t mq = (s * CQQ) % QQ;         // m mod q
        gq = (mq * GAM) % QQ;
    }
    uint32_t t = (uint32_t)(((uint64_t)b * IQP) % Q2);
    uint32_t r = P2 * t;                      // < n^2, exact
    uint32_t dp = m_from_r(r);                // flag case: b=0 -> r=0 -> 2480
    return gq | (dp << 16) | flag;
}

__global__ void build_tables(uint32_t* __restrict__ T) {
    int i = blockIdx.x * blockDim.x + threadIdx.x;
    if (i < TPN) T[i]       = (i < (int)P2) ? tp_entry((uint32_t)i) : 0u;
    if (i < TQN) T[TPN + i] = (i < (int)Q2) ? tq_entry((uint32_t)i) : 0u;
}

// ---- per-element decrypt: ~22 VALU ops + 2 LDS gathers, exact for ALL c ----
__device__ __forceinline__ float dec1(uint32_t c, const uint32_t* sTp,
                                      const uint32_t* sTq, float scale) {
    uint32_t up = sTp[mod24<P2>(c)];
    uint32_t uq = sTq[mod24<Q2>(c)];
    uint32_t gp  = up & 63u;
    uint32_t mp  = (up >> 8) & 63u;
    uint32_t dqv = (up >> 16) & 0xFFFu;
    uint32_t gq  = uq & 63u;
    uint32_t dpv = (uq >> 16) & 0xFFFu;
    uint32_t d = gq + QQ - gp;                // (m_q - m_p)*p^-1 mod q, premult
    d = min(d, d - QQ);
    uint32_t m = mad24_59(d, mp);             // CRT: m_p + 59*d ∈ [0, 3599)
    m = ((int32_t)uq < 0) ? dqv : m;          // q|c: table value from ip
    m = ((int32_t)up < 0) ? dpv : m;          // p|c: table value from iq (2480 if both)
    return fmaxf((float)m * scale, 0.0f);     // relu(m * (inv_scale/1000))
}

#define BLK 512

// R6 = round-0 structure (empirically unbeaten: 83us, VGPR 20, compiler-
// scheduled).  Depth sweep R0/R1/R2/R4 = 83/85/86/107us proved per-wave MLP
// restructuring cannot beat the compiler loop: the memory system drains this
// kernel at ~2.3 TB/s regardless of outstanding-request count.  One change:
// NON-TEMPORAL INPUT LOADS.  FETCH_SIZE=65.7MB (49% of the 134MB input) shows
// half the reads are absorbed by L3 and half miss -- the HBM-side read stream
// is scattered 64B misses (eviction noise picks which), wrecking DRAM burst
// efficiency vs m13's clean-miss 6.29 TB/s copy.  nt loads mark the
// single-use input evict-first/no-allocate: all reads become clean sequential
// HBM bursts.  Diagnostic: FETCH_SIZE must rise to ~131MB if nt is honored.
// (R6 fix: builtin needs an ext_vector pointer, not HIP_vector_type.)
__global__ __launch_bounds__(BLK, 8) void paillier_main(
        const uint32_t* __restrict__ in, float4* __restrict__ out,
        const uint32_t* __restrict__ T, const float* __restrict__ inv_scale,
        int n4) {
    __shared__ uint32_t sT[TT];
    for (int k = threadIdx.x; k < TT / 4; k += BLK)
        ((uint4*)sT)[k] = ((const uint4*)T)[k];
    __syncthreads();
    const uint32_t* sTp = sT;
    const uint32_t* sTq = sT + TPN;

    float scale = inv_scale[0] / 1000.0f;     // matches reference fp32 op order

    const u32x4* in4 = (const u32x4*)in;
    int stride = gridDim.x * BLK;
    for (int i = blockIdx.x * BLK + threadIdx.x; i < n4; i += stride) {
        u32x4 a = __builtin_nontemporal_load(in4 + i);   // 4 ciphertexts < 2^24
        float4 o;
        o.x = dec1(a.x, sTp, sTq, scale);
        o.y = dec1(a.y, sTp, sTq, scale);
        o.z = dec1(a.z, sTp, sTq, scale);
        o.w = dec1(a.w, sTp, sTq, scale);
        out[i] = o;                           // plain store (nt stores were
    }                                         // neutral-to-worse, R1/R2)
}

// Fallback (ws too small): build packed tables in-block, same dec path.
__global__ __launch_bounds__(BLK) void paillier_main_fb(
        const uint4* __restrict__ in4, float4* __restrict__ out,
        const float* __restrict__ inv_scale, int n4) {
    __shared__ uint32_t sT[TT];
    for (int i = threadIdx.x; i < (int)P2; i += BLK) sT[i]       = tp_entry((uint32_t)i);
    for (int i = threadIdx.x; i < (int)Q2; i += BLK) sT[TPN + i] = tq_entry((uint32_t)i);
    __syncthreads();
    const uint32_t* sTp = sT;
    const uint32_t* sTq = sT + TPN;
    float scale = inv_scale[0] / 1000.0f;
    int stride = gridDim.x * BLK;
    for (int i = blockIdx.x * BLK + threadIdx.x; i < n4; i += stride) {
        uint4 a = in4[i];
        float4 o;
        o.x = dec1(a.x, sTp, sTq, scale);
        o.y = dec1(a.y, sTp, sTq, scale);
        o.z = dec1(a.z, sTp, sTq, scale);
        o.w = dec1(a.w, sTp, sTq, scale);
        out[i] = o;
    }
}

extern "C" void kernel_launch(void* const* d_in, const int* in_sizes, int n_in,
                              void* d_out, int out_size, void* d_ws, size_t ws_size,
                              hipStream_t stream) {
    const uint32_t* c     = (const uint32_t*)d_in[0];  // int32 data
    const float* invscale = (const float*)d_in[1];
    float4* out           = (float4*)d_out;

    int n  = in_sizes[0];                              // 33,554,432
    int n4 = n / 4;

    int nblk = 1024;                                   // 4 blocks/CU, all resident
    int need = (n4 + BLK - 1) / BLK;
    if (nblk > need) nblk = need;

    if (ws_size >= WS_NEED && d_ws != nullptr) {
        uint32_t* T = (uint32_t*)d_ws;
        build_tables<<<(TQN + 255) / 256, 256, 0, stream>>>(T);
        paillier_main<<<nblk, BLK, 0, stream>>>(c, out, T, invscale, n4);
    } else {
        paillier_main_fb<<<nblk, BLK, 0, stream>>>((const uint4*)c, out, invscale, n4);
    }
}

// Round 8
// 225.453 us; speedup vs baseline: 1.1426x; 1.0061x over previous
//
#include <hip/hip_runtime.h>
#include <stdint.h>

// ---- Paillier constants (P=59, Q=61) ----
static constexpr uint32_t PP  = 59, QQ = 61;
static constexpr uint32_t Nn  = PP * QQ;        // 3599
static constexpr uint32_t P2  = PP * PP;        // 3481
static constexpr uint32_t Q2  = QQ * QQ;        // 3721
static constexpr uint32_t LAM = 1740;           // lcm(58,60)

constexpr uint32_t cinv(uint32_t a, uint32_t m) {   // brute-force modular inverse
    for (uint32_t x = 1; x < m; ++x) if ((uint64_t)a * x % m == 1u) return x;
    return 0u;
}
static constexpr uint32_t MU  = cinv(LAM % Nn, Nn);   // 1119 = lambda^-1 mod n
static constexpr uint32_t IQP = cinv(P2 % Q2, Q2);    // (p^2)^-1 mod q^2
static constexpr uint32_t GAM = cinv(PP % QQ, QQ);    // p^-1 mod q = 30
static constexpr uint32_t CPP = (cinv(QQ % PP, PP) * (MU % PP)) % PP;  // q^-1*mu mod p
static constexpr uint32_t CQQ = (cinv(PP % QQ, QQ) * (MU % QQ)) % QQ;  // p^-1*mu mod q

static constexpr int TPN = 3484;                // Tp u32 count (3481 padded to /4)
static constexpr int TQN = 3724;                // Tq u32 count (3721 padded to /4)
static constexpr int TT  = TPN + TQN;           // 7208 u32 = 28832 B
static constexpr size_t WS_NEED = (size_t)TT * 4;

typedef uint32_t u32x4 __attribute__((ext_vector_type(4)));   // builtin-compatible
typedef float    f32x4 __attribute__((ext_vector_type(4)));

// ---- full-rate 24-bit multiplies (operands provably < 2^24) ----
__device__ __forceinline__ uint32_t mul24lo(uint32_t a, uint32_t b) {
    uint32_t r;
    asm("v_mul_u32_u24 %0, %1, %2" : "=v"(r) : "v"(a), "v"(b));
    return r;
}
__device__ __forceinline__ uint32_t mul24hi(uint32_t a, uint32_t b) {
    uint32_t r;                                   // (u24(a)*u24(b)) >> 32
    asm("v_mul_hi_u32_u24 %0, %1, %2" : "=v"(r) : "v"(a), "v"(b));
    return r;
}
__device__ __forceinline__ uint32_t mad24_59(uint32_t a, uint32_t c) {
    uint32_t r;                                   // a*59 + c, all < 2^24
    asm("v_mad_u32_u24 %0, %1, 59, %2" : "=v"(r) : "v"(a), "v"(c));
    return r;
}

// x < 2^24, D ~ 3500: x mod D via 2^32 magic (no shift needed). Exact.
template<uint32_t D>
__device__ __forceinline__ uint32_t mod24(uint32_t x) {
    constexpr uint32_t M = (uint32_t)((1ull << 32) / D);
    uint32_t q = mul24hi(x, M);
    uint32_t r = x - mul24lo(q, D);           // ∈ [0, 2D)
    return min(r, r - D);                     // unsigned wrap trick
}

// ---- table construction (exact; runs once over 3724 threads) ----
template<uint32_t MOD>
__device__ uint32_t pow1740(uint32_t base) {
    uint32_t b = base % MOD, r = 1u, e = LAM;
    while (e) {                               // products < MOD^2 < 2^24
        if (e & 1u) r = (r * b) % MOD;
        b = (b * b) % MOD;
        e >>= 1u;
    }
    return r;
}
__device__ uint32_t m_from_r(uint32_t r) {
    if (r == 0u) return Nn - MU;              // x = -1 -> (-mu) mod n = 2480
    uint32_t x = (r - 1u) / Nn;               // exact floor, x < n
    return (x * MU) % Nn;                     // < 3599*1119 < 2^22
}
// Tp[ip]: bits0-5 g_p, bits8-13 m_p, bits16-27 dq_val (m when q|c), bit31 p|ip
__device__ uint32_t tp_entry(uint32_t i) {
    uint32_t a = pow1740<P2>(i);              // c^lam mod p^2 (0 iff p|i)
    uint32_t flag = (i % PP == 0u) ? 0x80000000u : 0u;
    uint32_t gp = 0u, mp = 0u;
    if (!flag) {                              // a ≡ 1 mod p; s = (a-1)/p
        uint32_t s = (a - 1u) / PP;
        mp = (s * CPP) % PP;                  // m mod p
        gp = (mp * GAM) % QQ;
    }
    uint32_t t = (uint32_t)(((uint64_t)((Q2 - a % Q2) % Q2) * IQP) % Q2);
    uint32_t r = a + P2 * t;                  // < n^2, exact
    uint32_t dq = m_from_r(r);                // flag case: a=0 -> r=0 -> 2480
    return gp | (mp << 8) | (dq << 16) | flag;
}
// Tq[iq]: bits0-5 g_q, bits16-27 dp_val (m when p|c), bit31 q|iq
__device__ uint32_t tq_entry(uint32_t i) {
    uint32_t b = pow1740<Q2>(i);              // c^lam mod q^2 (0 iff q|i)
    uint32_t flag = (i % QQ == 0u) ? 0x80000000u : 0u;
    uint32_t gq = 0u;
    if (!flag) {
        uint32_t s = (b - 1u) / QQ;
        uint32_t mq = (s * CQQ) % QQ;         // m mod q
        gq = (mq * GAM) % QQ;
    }
    uint32_t t = (uint32_t)(((uint64_t)b * IQP) % Q2);
    uint32_t r = P2 * t;                      // < n^2, exact
    uint32_t dp = m_from_r(r);                // flag case: b=0 -> r=0 -> 2480
    return gq | (dp << 16) | flag;
}

__global__ void build_tables(uint32_t* __restrict__ T) {
    int i = blockIdx.x * blockDim.x + threadIdx.x;
    if (i < TPN) T[i]       = (i < (int)P2) ? tp_entry((uint32_t)i) : 0u;
    if (i < TQN) T[TPN + i] = (i < (int)Q2) ? tq_entry((uint32_t)i) : 0u;
}

// ---- per-element decrypt: ~22 VALU ops + 2 LDS gathers, exact for ALL c ----
__device__ __forceinline__ float dec1(uint32_t c, const uint32_t* sTp,
                                      const uint32_t* sTq, float scale) {
    uint32_t up = sTp[mod24<P2>(c)];
    uint32_t uq = sTq[mod24<Q2>(c)];
    uint32_t gp  = up & 63u;
    uint32_t mp  = (up >> 8) & 63u;
    uint32_t dqv = (up >> 16) & 0xFFFu;
    uint32_t gq  = uq & 63u;
    uint32_t dpv = (uq >> 16) & 0xFFFu;
    uint32_t d = gq + QQ - gp;                // (m_q - m_p)*p^-1 mod q, premult
    d = min(d, d - QQ);
    uint32_t m = mad24_59(d, mp);             // CRT: m_p + 59*d ∈ [0, 3599)
    m = ((int32_t)uq < 0) ? dqv : m;          // q|c: table value from ip
    m = ((int32_t)up < 0) ? dpv : m;          // p|c: table value from iq (2480 if both)
    return fmaxf((float)m * scale, 0.0f);     // relu(m * (inv_scale/1000))
}

#define BLK 512

// R8 = R7 (nt loads, confirmed: main dropped below the 80us fill kernel,
// ~83 -> ~75us) + NON-TEMPORAL STORES.  Remaining theory: the 131MB output
// stream still write-allocates in L2/L3 -- 131MB of never-re-read lines
// churning the cache alongside the nt reads.  With nt on BOTH streams the
// traffic pattern equals m13's clean no-allocate streaming copy (6.3 TB/s).
// Prior "nt stores worse" evidence (R1/R2) was confounded by store-ack-gated
// hand schedules; this is the first clean test on the compiler-scheduled loop.
// Predict: main 75 -> 55-65us if right; 73-77us => write-alloc is free and
// this structure is within ~10% of its floor (declare roofline).
__global__ __launch_bounds__(BLK, 8) void paillier_main(
        const uint32_t* __restrict__ in, float* __restrict__ outp,
        const uint32_t* __restrict__ T, const float* __restrict__ inv_scale,
        int n4) {
    __shared__ uint32_t sT[TT];
    for (int k = threadIdx.x; k < TT / 4; k += BLK)
        ((uint4*)sT)[k] = ((const uint4*)T)[k];
    __syncthreads();
    const uint32_t* sTp = sT;
    const uint32_t* sTq = sT + TPN;

    float scale = inv_scale[0] / 1000.0f;     // matches reference fp32 op order

    const u32x4* in4 = (const u32x4*)in;
    f32x4* out4      = (f32x4*)outp;
    int stride = gridDim.x * BLK;
    for (int i = blockIdx.x * BLK + threadIdx.x; i < n4; i += stride) {
        u32x4 a = __builtin_nontemporal_load(in4 + i);   // 4 ciphertexts < 2^24
        f32x4 o;
        o.x = dec1(a.x, sTp, sTq, scale);
        o.y = dec1(a.y, sTp, sTq, scale);
        o.z = dec1(a.z, sTp, sTq, scale);
        o.w = dec1(a.w, sTp, sTq, scale);
        __builtin_nontemporal_store(o, out4 + i);
    }
}

// Fallback (ws too small): build packed tables in-block, same dec path.
__global__ __launch_bounds__(BLK) void paillier_main_fb(
        const uint4* __restrict__ in4, float4* __restrict__ out,
        const float* __restrict__ inv_scale, int n4) {
    __shared__ uint32_t sT[TT];
    for (int i = threadIdx.x; i < (int)P2; i += BLK) sT[i]       = tp_entry((uint32_t)i);
    for (int i = threadIdx.x; i < (int)Q2; i += BLK) sT[TPN + i] = tq_entry((uint32_t)i);
    __syncthreads();
    const uint32_t* sTp = sT;
    const uint32_t* sTq = sT + TPN;
    float scale = inv_scale[0] / 1000.0f;
    int stride = gridDim.x * BLK;
    for (int i = blockIdx.x * BLK + threadIdx.x; i < n4; i += stride) {
        uint4 a = in4[i];
        float4 o;
        o.x = dec1(a.x, sTp, sTq, scale);
        o.y = dec1(a.y, sTp, sTq, scale);
        o.z = dec1(a.z, sTp, sTq, scale);
        o.w = dec1(a.w, sTp, sTq, scale);
        out[i] = o;
    }
}

extern "C" void kernel_launch(void* const* d_in, const int* in_sizes, int n_in,
                              void* d_out, int out_size, void* d_ws, size_t ws_size,
                              hipStream_t stream) {
    const uint32_t* c     = (const uint32_t*)d_in[0];  // int32 data
    const float* invscale = (const float*)d_in[1];

    int n  = in_sizes[0];                              // 33,554,432
    int n4 = n / 4;

    int nblk = 1024;                                   // 4 blocks/CU, all resident
    int need = (n4 + BLK - 1) / BLK;
    if (nblk > need) nblk = need;

    if (ws_size >= WS_NEED && d_ws != nullptr) {
        uint32_t* T = (uint32_t*)d_ws;
        build_tables<<<(TQN + 255) / 256, 256, 0, stream>>>(T);
        paillier_main<<<nblk, BLK, 0, stream>>>(c, (float*)d_out, T, invscale, n4);
    } else {
        paillier_main_fb<<<nblk, BLK, 0, stream>>>((const uint4*)c, (float4*)d_out,
                                                   invscale, n4);
    }
}